// Round 3
// baseline (663.709 us; speedup 1.0000x reference)
//
#include <hip/hip_runtime.h>
#include <stdint.h>

typedef _Float16 half8 __attribute__((ext_vector_type(8)));
typedef float floatx4 __attribute__((ext_vector_type(4)));

__device__ __forceinline__ uint16_t f16bits(_Float16 h) {
  union { _Float16 f; uint16_t u; } x; x.f = h; return x.u;
}

// async global->LDS, 16B per lane; lds dst is wave-uniform base + lane*16
__device__ __forceinline__ void g2l16(const void* g, void* l) {
  __builtin_amdgcn_global_load_lds((const __attribute__((address_space(1))) void*)g,
                                   (__attribute__((address_space(3))) void*)l,
                                   16, 0, 0);
}

// ---------------- split fp32 -> f16 hi + f16 lo ----------------
__global__ __launch_bounds__(256) void split_f16_kernel(
    const float* __restrict__ x, uint16_t* __restrict__ hi,
    uint16_t* __restrict__ lo, int n4) {
  int i = blockIdx.x * 256 + threadIdx.x;
  if (i >= n4) return;
  float4 v = ((const float4*)x)[i];
  ushort4 h, l;
  _Float16 a;
  a = (_Float16)v.x; h.x = f16bits(a); l.x = f16bits((_Float16)(v.x - (float)a));
  a = (_Float16)v.y; h.y = f16bits(a); l.y = f16bits((_Float16)(v.y - (float)a));
  a = (_Float16)v.z; h.z = f16bits(a); l.z = f16bits((_Float16)(v.z - (float)a));
  a = (_Float16)v.w; h.w = f16bits(a); l.w = f16bits((_Float16)(v.w - (float)a));
  ((ushort4*)hi)[i] = h;
  ((ushort4*)lo)[i] = l;
}

// ---------------- C = A * B^T  (128x128 tile, BK=32) ----------------
// A:(M,K) row-major f16 (hi[,lo]), B:(N,K) row-major f16 (hi[,lo]).
// hi tiles staged in LDS via global_load_lds; lo fragments are demand-loaded
// DIRECTLY from global (16 rows x 64B pattern, L1/L2 served) -> halves LDS
// traffic per block-kt (96KB -> 48KB).
// SPLIT: acc += Ahi*Bhi + Ahi*Blo + Alo*Bhi  (double-f16 ~ fp32 accuracy)
// XCD swizzle: lin = by*8+bx; bx'=(lin>>3)&7, by'=(lin&7)|((lin>>6)<<3)
// -> each XCD walks one M-band with N inner (B panel L2-resident).
// MODE 0: write split f16 (Chi,Clo), add bias[col]
// MODE 1: write f32 Cf, add mask (same layout/batch stride as C)
// MODE 2: write f32 Cf
template <bool SPLIT, int MODE>
__global__ __launch_bounds__(256, 4) void gemm_bt(
    const uint16_t* __restrict__ Ahi, const uint16_t* __restrict__ Alo,
    const uint16_t* __restrict__ Bhi, const uint16_t* __restrict__ Blo,
    uint16_t* __restrict__ Chi, uint16_t* __restrict__ Clo,
    float* __restrict__ Cf, const float* __restrict__ mask,
    const float* __restrict__ bias, int N, int K,
    long batchA, long batchB, long batchC) {
  __shared__ __align__(16) uint16_t sA[128 * 32];
  __shared__ __align__(16) uint16_t sB[128 * 32];

  const int tid = threadIdx.x;
  const int lane = tid & 63;
  const int w = tid >> 6;            // wave 0..3
  const int wr = w >> 1, wc = w & 1; // 2x2 wave grid, 64x64 per wave
  const int quad = lane >> 4, l16 = lane & 15;

  // XCD-aware block swizzle (gridDim.x == 8 in all uses)
  const int lin = blockIdx.y * 8 + blockIdx.x;
  const int bx = (lin >> 3) & 7;
  const int by = (lin & 7) | ((lin >> 6) << 3);

  const int m0 = by * 128;
  const int n0 = bx * 128;
  const size_t zA = (size_t)blockIdx.z * batchA;
  const size_t zB = (size_t)blockIdx.z * batchB;
  const size_t zC = (size_t)blockIdx.z * batchC;

  // staging: wave w loads rows [w*32, w*32+32) of each hi 128x32 tile, 2x 1KB
  const int r0 = w * 32 + (lane >> 2);                       // row for q=0 chunk
  const int ldc = (((lane & 3) ^ ((lane >> 2) & 3)) * 16);   // XOR-swizzled chunk

  const char* gAh0 = (const char*)(Ahi + zA + (size_t)(m0 + r0) * K) + ldc;
  const char* gAh1 = gAh0 + (size_t)16 * K * 2;
  const char* gBh0 = (const char*)(Bhi + zB + (size_t)(n0 + r0) * K) + ldc;
  const char* gBh1 = gBh0 + (size_t)16 * K * 2;
  uint16_t* lA0 = &sA[(w * 32) * 32];
  uint16_t* lA1 = &sA[(w * 32 + 16) * 32];
  uint16_t* lB0 = &sB[(w * 32) * 32];
  uint16_t* lB1 = &sB[(w * 32 + 16) * 32];

  // direct-from-global lo fragment bases (A-operand layout: row=l16, k=quad*8)
  const char* pAlo = nullptr;
  const char* pBlo = nullptr;
  if constexpr (SPLIT) {
    pAlo = (const char*)(Alo + zA + (size_t)(m0 + wr * 64 + l16) * K) + quad * 16;
    pBlo = (const char*)(Blo + zB + (size_t)(n0 + wc * 64 + l16) * K) + quad * 16;
  }
  const size_t fstride = (size_t)32 * K;  // 16 rows * K * 2B

  // compute-phase LDS offsets (elements); chunk swizzled by row&3 == l16&3
  const int aoff = (wr * 64 + l16) * 32 + ((quad ^ (l16 & 3)) * 8);
  const int boff = (wc * 64 + l16) * 32 + ((quad ^ (l16 & 3)) * 8);

  floatx4 acc[4][4];
  floatx4 zero = {0.f, 0.f, 0.f, 0.f};
#pragma unroll
  for (int i = 0; i < 4; ++i)
#pragma unroll
    for (int j = 0; j < 4; ++j) acc[i][j] = zero;

  const int nkt = K >> 5;
  for (int kt = 0; kt < nkt; ++kt) {
    const int kb = kt * 64;  // 32 f16 = 64B per row per K-tile
    g2l16(gAh0 + kb, lA0);
    g2l16(gAh1 + kb, lA1);
    g2l16(gBh0 + kb, lB0);
    g2l16(gBh1 + kb, lB1);
    __syncthreads();  // drains vmcnt then barrier

    half8 fa[4], fbh[4];
#pragma unroll
    for (int i = 0; i < 4; ++i) fa[i] = *(const half8*)&sA[aoff + i * 512];
#pragma unroll
    for (int j = 0; j < 4; ++j) fbh[j] = *(const half8*)&sB[boff + j * 512];

    // pass 1: hi x hi (gives lo demand-loads latency slack)
#pragma unroll
    for (int i = 0; i < 4; ++i)
#pragma unroll
      for (int j = 0; j < 4; ++j)
        acc[i][j] = __builtin_amdgcn_mfma_f32_16x16x32_f16(fa[i], fbh[j], acc[i][j], 0, 0, 0);

    if constexpr (SPLIT) {
      // pass 2: Ahi x Blo (Blo frags direct from global)
      half8 fbl[4];
#pragma unroll
      for (int j = 0; j < 4; ++j)
        fbl[j] = *(const half8*)(pBlo + (size_t)j * fstride + kb);
#pragma unroll
      for (int i = 0; i < 4; ++i)
#pragma unroll
        for (int j = 0; j < 4; ++j)
          acc[i][j] = __builtin_amdgcn_mfma_f32_16x16x32_f16(fa[i], fbl[j], acc[i][j], 0, 0, 0);
      // pass 3: Alo x Bhi (Alo frags direct from global)
      half8 fal[4];
#pragma unroll
      for (int i = 0; i < 4; ++i)
        fal[i] = *(const half8*)(pAlo + (size_t)i * fstride + kb);
#pragma unroll
      for (int i = 0; i < 4; ++i)
#pragma unroll
        for (int j = 0; j < 4; ++j)
          acc[i][j] = __builtin_amdgcn_mfma_f32_16x16x32_f16(fal[i], fbh[j], acc[i][j], 0, 0, 0);
    }
    __syncthreads();  // protect LDS before next stage
  }

  // epilogue: C/D layout col=lane&15, row=quad*4+r (m89/m91 verified)
  const int crow0 = m0 + wr * 64 + quad * 4;
  const int ccol0 = n0 + wc * 64 + l16;
#pragma unroll
  for (int j = 0; j < 4; ++j) {
    const int col = ccol0 + j * 16;
    float bj = 0.f;
    if constexpr (MODE == 0) bj = bias[col];
#pragma unroll
    for (int i = 0; i < 4; ++i) {
#pragma unroll
      for (int r = 0; r < 4; ++r) {
        const int row = crow0 + i * 16 + r;
        const size_t idx = zC + (size_t)row * N + col;
        float v = acc[i][j][r];
        if constexpr (MODE == 0) {
          v += bj;
          _Float16 h = (_Float16)v;
          Chi[idx] = f16bits(h);
          Clo[idx] = f16bits((_Float16)(v - (float)h));
        } else if constexpr (MODE == 1) {
          Cf[idx] = v + mask[idx];
        } else {
          Cf[idx] = v;
        }
      }
    }
  }
}

// ---------------- row softmax: fp32 scores -> f16 probs ----------------
__global__ __launch_bounds__(256) void softmax_kernel(
    const float* __restrict__ sc, uint16_t* __restrict__ p) {
  const int row = blockIdx.x;
  const float* x = sc + (size_t)row * 1024;
  const int t = threadIdx.x;
  float4 v = ((const float4*)x)[t];
  float m = fmaxf(fmaxf(v.x, v.y), fmaxf(v.z, v.w));
#pragma unroll
  for (int off = 32; off; off >>= 1) m = fmaxf(m, __shfl_xor(m, off));
  __shared__ float redm[4];
  __shared__ float reds[4];
  const int wv = t >> 6, ln = t & 63;
  if (ln == 0) redm[wv] = m;
  __syncthreads();
  m = fmaxf(fmaxf(redm[0], redm[1]), fmaxf(redm[2], redm[3]));
  float e0 = __expf(v.x - m), e1 = __expf(v.y - m);
  float e2 = __expf(v.z - m), e3 = __expf(v.w - m);
  float s = e0 + e1 + e2 + e3;
#pragma unroll
  for (int off = 32; off; off >>= 1) s += __shfl_xor(s, off);
  if (ln == 0) reds[wv] = s;
  __syncthreads();
  s = reds[0] + reds[1] + reds[2] + reds[3];
  float inv = 1.f / s;
  ushort4 o;
  o.x = f16bits((_Float16)(e0 * inv));
  o.y = f16bits((_Float16)(e1 * inv));
  o.z = f16bits((_Float16)(e2 * inv));
  o.w = f16bits((_Float16)(e3 * inv));
  ((ushort4*)(p + (size_t)row * 1024))[t] = o;
}

// ---------------- H (b,t,e) fp32 -> H_T (b,e,t) f16 ----------------
__global__ __launch_bounds__(256) void transpose_f16_kernel(
    const float* __restrict__ src, uint16_t* __restrict__ dst) {
  __shared__ uint16_t tile[64][65];
  const int e0 = blockIdx.x * 64;
  const int t0 = blockIdx.y * 64;
  const size_t bb = (size_t)blockIdx.z << 20;  // 1024*1024 per batch
  const int r = threadIdx.x >> 4;
  const int c = (threadIdx.x & 15) * 4;
#pragma unroll
  for (int it = 0; it < 4; ++it) {
    const int tr = r + it * 16;
    float4 v = *(const float4*)(src + bb + (size_t)(t0 + tr) * 1024 + e0 + c);
    tile[c + 0][tr] = f16bits((_Float16)v.x);
    tile[c + 1][tr] = f16bits((_Float16)v.y);
    tile[c + 2][tr] = f16bits((_Float16)v.z);
    tile[c + 3][tr] = f16bits((_Float16)v.w);
  }
  __syncthreads();
#pragma unroll
  for (int it = 0; it < 4; ++it) {
    const int er = r + it * 16;
    ushort4 o;
    o.x = tile[er][c + 0];
    o.y = tile[er][c + 1];
    o.z = tile[er][c + 2];
    o.w = tile[er][c + 3];
    *(ushort4*)(dst + bb + (size_t)(e0 + er) * 1024 + t0 + c) = o;
  }
}

extern "C" void kernel_launch(void* const* d_in, const int* in_sizes, int n_in,
                              void* d_out, int out_size, void* d_ws, size_t ws_size,
                              hipStream_t stream) {
  (void)in_sizes; (void)n_in; (void)out_size; (void)ws_size;
  const float* S    = (const float*)d_in[0];  // (16,1024,1024)
  const float* H    = (const float*)d_in[1];  // (16,1024,1024)
  const float* mask = (const float*)d_in[2];  // (16,1024,1024)
  const float* Ww   = (const float*)d_in[3];  // (1024,1024)
  const float* Wb   = (const float*)d_in[4];  // (1024,)
  float* out = (float*)d_out;
  char* ws = (char*)d_ws;
  const size_t MB = 1024ull * 1024ull;

  // workspace layout (peak 196MB):
  uint16_t* Whi  = (uint16_t*)(ws + 0 * MB);    // 2MB
  uint16_t* Wlo  = (uint16_t*)(ws + 2 * MB);    // 2MB
  uint16_t* Pjhi = (uint16_t*)(ws + 4 * MB);    // 32MB  projection hi
  uint16_t* Pjlo = (uint16_t*)(ws + 36 * MB);   // 32MB  projection lo
  uint16_t* Hhi  = (uint16_t*)(ws + 68 * MB);   // 32MB
  uint16_t* Hlo  = (uint16_t*)(ws + 100 * MB);  // 32MB
  uint16_t* Shi  = (uint16_t*)(ws + 132 * MB);  // 32MB (dead after gemm1)
  uint16_t* Slo  = (uint16_t*)(ws + 164 * MB);  // 32MB (dead after gemm1)
  float*    SC   = (float*)(ws + 132 * MB);     // 64MB scores, aliases Shi/Slo
  uint16_t* PR   = (uint16_t*)(ws + 68 * MB);   // 32MB probs, aliases Hhi
  uint16_t* HT   = (uint16_t*)(ws + 100 * MB);  // 32MB H^T f16, aliases Hlo

  // split inputs into f16 hi/lo
  split_f16_kernel<<<16384, 256, 0, stream>>>(S, Shi, Slo, 4 * 1024 * 1024);
  split_f16_kernel<<<16384, 256, 0, stream>>>(H, Hhi, Hlo, 4 * 1024 * 1024);
  split_f16_kernel<<<1024, 256, 0, stream>>>(Ww, Whi, Wlo, 256 * 1024);

  // S_ = S @ W^T + b   (M=16384 folded into blockIdx.y)
  gemm_bt<true, 0><<<dim3(8, 128, 1), 256, 0, stream>>>(
      Shi, Slo, Whi, Wlo, Pjhi, Pjlo, nullptr, nullptr, Wb,
      1024, 1024, 0, 0, 0);
  // scores = S_ @ H^T + mask   (batched, 16)
  gemm_bt<true, 1><<<dim3(8, 8, 16), 256, 0, stream>>>(
      Pjhi, Pjlo, Hhi, Hlo, nullptr, nullptr, SC, mask, nullptr,
      1024, 1024, 1048576, 1048576, 1048576);
  // P = softmax(scores) rowwise -> f16
  softmax_kernel<<<16384, 256, 0, stream>>>(SC, PR);
  // H_T f16
  transpose_f16_kernel<<<dim3(16, 16, 16), 256, 0, stream>>>(H, HT);
  // out = P @ H  ==  P @ (H_T)^T
  gemm_bt<false, 2><<<dim3(8, 8, 16), 256, 0, stream>>>(
      PR, nullptr, HT, nullptr, nullptr, nullptr, out, nullptr, nullptr,
      1024, 1024, 1048576, 1048576, 1048576);
}

// Round 4
// 522.976 us; speedup vs baseline: 1.2691x; 1.2691x over previous
//
#include <hip/hip_runtime.h>
#include <stdint.h>

typedef _Float16 half8 __attribute__((ext_vector_type(8)));
typedef float floatx4 __attribute__((ext_vector_type(4)));

__device__ __forceinline__ uint16_t f16bits(_Float16 h) {
  union { _Float16 f; uint16_t u; } x; x.f = h; return x.u;
}

// async global->LDS, 16B per lane; lds dst is wave-uniform base + lane*16
__device__ __forceinline__ void g2l16(const void* g, void* l) {
  __builtin_amdgcn_global_load_lds((const __attribute__((address_space(1))) void*)g,
                                   (__attribute__((address_space(3))) void*)l,
                                   16, 0, 0);
}

// ---------------- split fp32 -> f16 hi + f16 lo ----------------
__global__ __launch_bounds__(256) void split_f16_kernel(
    const float* __restrict__ x, uint16_t* __restrict__ hi,
    uint16_t* __restrict__ lo, int n4) {
  int i = blockIdx.x * 256 + threadIdx.x;
  if (i >= n4) return;
  float4 v = ((const float4*)x)[i];
  ushort4 h, l;
  _Float16 a;
  a = (_Float16)v.x; h.x = f16bits(a); l.x = f16bits((_Float16)(v.x - (float)a));
  a = (_Float16)v.y; h.y = f16bits(a); l.y = f16bits((_Float16)(v.y - (float)a));
  a = (_Float16)v.z; h.z = f16bits(a); l.z = f16bits((_Float16)(v.z - (float)a));
  a = (_Float16)v.w; h.w = f16bits(a); l.w = f16bits((_Float16)(v.w - (float)a));
  ((ushort4*)hi)[i] = h;
  ((ushort4*)lo)[i] = l;
}

// ---------------- fused H split + transpose ----------------
// H (b,t,e) f32 -> Hhi,Hlo (b,t,e) f16  AND  HT (b,e,t) f16(=hi)
__global__ __launch_bounds__(256) void split_h_kernel(
    const float* __restrict__ src, uint16_t* __restrict__ hi,
    uint16_t* __restrict__ lo, uint16_t* __restrict__ ht) {
  __shared__ uint16_t tile[64][65];
  const int e0 = blockIdx.x * 64;
  const int t0 = blockIdx.y * 64;
  const size_t bb = (size_t)blockIdx.z << 20;  // 1024*1024 per batch
  const int r = threadIdx.x >> 4;        // 0..15
  const int c = (threadIdx.x & 15) * 4;  // 0..60
#pragma unroll
  for (int it = 0; it < 4; ++it) {
    const int tr = r + it * 16;
    const size_t idx = bb + (size_t)(t0 + tr) * 1024 + e0 + c;
    float4 v = *(const float4*)(src + idx);
    ushort4 h, l;
    _Float16 a;
    a = (_Float16)v.x; h.x = f16bits(a); l.x = f16bits((_Float16)(v.x - (float)a));
    a = (_Float16)v.y; h.y = f16bits(a); l.y = f16bits((_Float16)(v.y - (float)a));
    a = (_Float16)v.z; h.z = f16bits(a); l.z = f16bits((_Float16)(v.z - (float)a));
    a = (_Float16)v.w; h.w = f16bits(a); l.w = f16bits((_Float16)(v.w - (float)a));
    *(ushort4*)(hi + idx) = h;
    *(ushort4*)(lo + idx) = l;
    tile[c + 0][tr] = h.x;
    tile[c + 1][tr] = h.y;
    tile[c + 2][tr] = h.z;
    tile[c + 3][tr] = h.w;
  }
  __syncthreads();
#pragma unroll
  for (int it = 0; it < 4; ++it) {
    const int er = r + it * 16;
    ushort4 o;
    o.x = tile[er][c + 0];
    o.y = tile[er][c + 1];
    o.z = tile[er][c + 2];
    o.w = tile[er][c + 3];
    *(ushort4*)(ht + bb + (size_t)(e0 + er) * 1024 + t0 + c) = o;
  }
}

// ---------------- C = A * B^T  (128x128 tile, BK=32) ----------------
// A:(M,K) row-major f16 (hi[,lo]), B:(N,K) row-major f16 (hi[,lo]).
// SPLIT: acc += Ahi*Blo + Ahi*Bhi + Alo*Bhi  (double-f16 ~ fp32 accuracy)
// GMAP 0: x = M-tile (fastest -> lin%8 partitions M across XCDs; A read once
//         per device), y = N-tile, z = 0.   (for the M=16384 projection)
// GMAP 1: x = batch (lin%8 partitions batches across XCDs; each XCD streams
//         its 2 batches' A and B exactly once), y = (m<<3)|n.
// MODE 0: write split f16 (Chi,Clo), add bias[col]
// MODE 1: write f32 Cf, add mask (same layout/batch stride as C)
// MODE 2: write f32 Cf
template <bool SPLIT, int MODE, int GMAP>
__global__ __launch_bounds__(256, 4) void gemm_bt(
    const uint16_t* __restrict__ Ahi, const uint16_t* __restrict__ Alo,
    const uint16_t* __restrict__ Bhi, const uint16_t* __restrict__ Blo,
    uint16_t* __restrict__ Chi, uint16_t* __restrict__ Clo,
    float* __restrict__ Cf, const float* __restrict__ mask,
    const float* __restrict__ bias, int N, int K,
    long batchA, long batchB, long batchC) {
  constexpr int NBUF = SPLIT ? 2 : 1;
  constexpr int LOI = SPLIT ? 1 : 0;
  __shared__ __align__(16) uint16_t sA[NBUF][128 * 32];
  __shared__ __align__(16) uint16_t sB[NBUF][128 * 32];

  const int tid = threadIdx.x;
  const int lane = tid & 63;
  const int w = tid >> 6;            // wave 0..3
  const int wr = w >> 1, wc = w & 1; // 2x2 wave grid, 64x64 per wave
  const int quad = lane >> 4, l16 = lane & 15;

  int m_t, n_t, z;
  if constexpr (GMAP == 0) {
    m_t = blockIdx.x; n_t = blockIdx.y; z = 0;
  } else {
    z = blockIdx.x; m_t = blockIdx.y >> 3; n_t = blockIdx.y & 7;
  }
  const int m0 = m_t * 128;
  const int n0 = n_t * 128;
  const size_t zA = (size_t)z * batchA;
  const size_t zB = (size_t)z * batchB;
  const size_t zC = (size_t)z * batchC;

  // staging: wave w loads rows [w*32, w*32+32) of each 128x32 tile, 2x 1KB
  const int r0 = w * 32 + (lane >> 2);                       // row for q=0 chunk
  const int ldc = (((lane & 3) ^ ((lane >> 2) & 3)) * 16);   // XOR-swizzled chunk

  const char* gAh0 = (const char*)(Ahi + zA + (size_t)(m0 + r0) * K) + ldc;
  const char* gAh1 = gAh0 + (size_t)16 * K * 2;
  const char* gBh0 = (const char*)(Bhi + zB + (size_t)(n0 + r0) * K) + ldc;
  const char* gBh1 = gBh0 + (size_t)16 * K * 2;
  const char* gAl0 = gAh0; const char* gAl1 = gAh1;
  const char* gBl0 = gBh0; const char* gBl1 = gBh1;
  if constexpr (SPLIT) {
    gAl0 = (const char*)(Alo + zA + (size_t)(m0 + r0) * K) + ldc;
    gAl1 = gAl0 + (size_t)16 * K * 2;
    gBl0 = (const char*)(Blo + zB + (size_t)(n0 + r0) * K) + ldc;
    gBl1 = gBl0 + (size_t)16 * K * 2;
  }
  uint16_t* lA0 = &sA[0][(w * 32) * 32];
  uint16_t* lA1 = &sA[0][(w * 32 + 16) * 32];
  uint16_t* lB0 = &sB[0][(w * 32) * 32];
  uint16_t* lB1 = &sB[0][(w * 32 + 16) * 32];
  uint16_t* lA0l = &sA[LOI][(w * 32) * 32];
  uint16_t* lA1l = &sA[LOI][(w * 32 + 16) * 32];
  uint16_t* lB0l = &sB[LOI][(w * 32) * 32];
  uint16_t* lB1l = &sB[LOI][(w * 32 + 16) * 32];

  // compute-phase LDS offsets (elements); chunk swizzled by row&3 == l16&3
  const int aoff = (wr * 64 + l16) * 32 + ((quad ^ (l16 & 3)) * 8);
  const int boff = (wc * 64 + l16) * 32 + ((quad ^ (l16 & 3)) * 8);

  floatx4 acc[4][4];
  floatx4 zero = {0.f, 0.f, 0.f, 0.f};
#pragma unroll
  for (int i = 0; i < 4; ++i)
#pragma unroll
    for (int j = 0; j < 4; ++j) acc[i][j] = zero;

  const int nkt = K >> 5;
  for (int kt = 0; kt < nkt; ++kt) {
    const int kb = kt * 64;  // 32 f16 = 64B per row per K-tile
    g2l16(gAh0 + kb, lA0);
    g2l16(gAh1 + kb, lA1);
    g2l16(gBh0 + kb, lB0);
    g2l16(gBh1 + kb, lB1);
    if constexpr (SPLIT) {
      g2l16(gAl0 + kb, lA0l);
      g2l16(gAl1 + kb, lA1l);
      g2l16(gBl0 + kb, lB0l);
      g2l16(gBl1 + kb, lB1l);
    }
    __syncthreads();  // drains vmcnt then barrier

    // 3 sequential product passes -> max ~2x4 half8 frags live (fits 128 V+A)
    half8 fa[4];
#pragma unroll
    for (int i = 0; i < 4; ++i) fa[i] = *(const half8*)&sA[0][aoff + i * 512];
    if constexpr (SPLIT) {
      half8 fbl[4];
#pragma unroll
      for (int j = 0; j < 4; ++j) fbl[j] = *(const half8*)&sB[1][boff + j * 512];
#pragma unroll
      for (int i = 0; i < 4; ++i)
#pragma unroll
        for (int j = 0; j < 4; ++j)
          acc[i][j] = __builtin_amdgcn_mfma_f32_16x16x32_f16(fa[i], fbl[j], acc[i][j], 0, 0, 0);
    }
    half8 fbh[4];
#pragma unroll
    for (int j = 0; j < 4; ++j) fbh[j] = *(const half8*)&sB[0][boff + j * 512];
#pragma unroll
    for (int i = 0; i < 4; ++i)
#pragma unroll
      for (int j = 0; j < 4; ++j)
        acc[i][j] = __builtin_amdgcn_mfma_f32_16x16x32_f16(fa[i], fbh[j], acc[i][j], 0, 0, 0);
    if constexpr (SPLIT) {
      half8 fal[4];
#pragma unroll
      for (int i = 0; i < 4; ++i) fal[i] = *(const half8*)&sA[1][aoff + i * 512];
#pragma unroll
      for (int i = 0; i < 4; ++i)
#pragma unroll
        for (int j = 0; j < 4; ++j)
          acc[i][j] = __builtin_amdgcn_mfma_f32_16x16x32_f16(fal[i], fbh[j], acc[i][j], 0, 0, 0);
    }
    __syncthreads();  // protect LDS before next stage
  }

  // epilogue: C/D layout col=lane&15, row=quad*4+r (m89/m91 verified)
  const int crow0 = m0 + wr * 64 + quad * 4;
  const int ccol0 = n0 + wc * 64 + l16;
#pragma unroll
  for (int j = 0; j < 4; ++j) {
    const int col = ccol0 + j * 16;
    float bj = 0.f;
    if constexpr (MODE == 0) bj = bias[col];
#pragma unroll
    for (int i = 0; i < 4; ++i) {
#pragma unroll
      for (int r = 0; r < 4; ++r) {
        const int row = crow0 + i * 16 + r;
        const size_t idx = zC + (size_t)row * N + col;
        float v = acc[i][j][r];
        if constexpr (MODE == 0) {
          v += bj;
          _Float16 h = (_Float16)v;
          Chi[idx] = f16bits(h);
          Clo[idx] = f16bits((_Float16)(v - (float)h));
        } else if constexpr (MODE == 1) {
          Cf[idx] = v + mask[idx];
        } else {
          Cf[idx] = v;
        }
      }
    }
  }
}

// ---------------- row softmax: fp32 scores -> f16 probs ----------------
__global__ __launch_bounds__(256) void softmax_kernel(
    const float* __restrict__ sc, uint16_t* __restrict__ p) {
  const int row = blockIdx.x;
  const float* x = sc + (size_t)row * 1024;
  const int t = threadIdx.x;
  float4 v = ((const float4*)x)[t];
  float m = fmaxf(fmaxf(v.x, v.y), fmaxf(v.z, v.w));
#pragma unroll
  for (int off = 32; off; off >>= 1) m = fmaxf(m, __shfl_xor(m, off));
  __shared__ float redm[4];
  __shared__ float reds[4];
  const int wv = t >> 6, ln = t & 63;
  if (ln == 0) redm[wv] = m;
  __syncthreads();
  m = fmaxf(fmaxf(redm[0], redm[1]), fmaxf(redm[2], redm[3]));
  float e0 = __expf(v.x - m), e1 = __expf(v.y - m);
  float e2 = __expf(v.z - m), e3 = __expf(v.w - m);
  float s = e0 + e1 + e2 + e3;
#pragma unroll
  for (int off = 32; off; off >>= 1) s += __shfl_xor(s, off);
  if (ln == 0) reds[wv] = s;
  __syncthreads();
  s = reds[0] + reds[1] + reds[2] + reds[3];
  float inv = 1.f / s;
  ushort4 o;
  o.x = f16bits((_Float16)(e0 * inv));
  o.y = f16bits((_Float16)(e1 * inv));
  o.z = f16bits((_Float16)(e2 * inv));
  o.w = f16bits((_Float16)(e3 * inv));
  ((ushort4*)(p + (size_t)row * 1024))[t] = o;
}

// ---------------- H (b,t,e) f32 -> H_T (b,e,t) f16 (fallback path) --------
__global__ __launch_bounds__(256) void transpose_f16_kernel(
    const float* __restrict__ src, uint16_t* __restrict__ dst) {
  __shared__ uint16_t tile[64][65];
  const int e0 = blockIdx.x * 64;
  const int t0 = blockIdx.y * 64;
  const size_t bb = (size_t)blockIdx.z << 20;
  const int r = threadIdx.x >> 4;
  const int c = (threadIdx.x & 15) * 4;
#pragma unroll
  for (int it = 0; it < 4; ++it) {
    const int tr = r + it * 16;
    float4 v = *(const float4*)(src + bb + (size_t)(t0 + tr) * 1024 + e0 + c);
    tile[c + 0][tr] = f16bits((_Float16)v.x);
    tile[c + 1][tr] = f16bits((_Float16)v.y);
    tile[c + 2][tr] = f16bits((_Float16)v.z);
    tile[c + 3][tr] = f16bits((_Float16)v.w);
  }
  __syncthreads();
#pragma unroll
  for (int it = 0; it < 4; ++it) {
    const int er = r + it * 16;
    ushort4 o;
    o.x = tile[er][c + 0];
    o.y = tile[er][c + 1];
    o.z = tile[er][c + 2];
    o.w = tile[er][c + 3];
    *(ushort4*)(dst + bb + (size_t)(e0 + er) * 1024 + t0 + c) = o;
  }
}

extern "C" void kernel_launch(void* const* d_in, const int* in_sizes, int n_in,
                              void* d_out, int out_size, void* d_ws, size_t ws_size,
                              hipStream_t stream) {
  (void)in_sizes; (void)n_in; (void)out_size;
  const float* S    = (const float*)d_in[0];  // (16,1024,1024)
  const float* H    = (const float*)d_in[1];  // (16,1024,1024)
  const float* mask = (const float*)d_in[2];  // (16,1024,1024)
  const float* Ww   = (const float*)d_in[3];  // (1024,1024)
  const float* Wb   = (const float*)d_in[4];  // (1024,)
  float* out = (float*)d_out;
  char* ws = (char*)d_ws;
  const size_t MB = 1024ull * 1024ull;

  // workspace layout:
  uint16_t* Whi  = (uint16_t*)(ws + 0 * MB);    // 2MB
  uint16_t* Wlo  = (uint16_t*)(ws + 2 * MB);    // 2MB
  uint16_t* Pjhi = (uint16_t*)(ws + 4 * MB);    // 32MB  projection hi
  uint16_t* Pjlo = (uint16_t*)(ws + 36 * MB);   // 32MB  projection lo
  uint16_t* Hhi  = (uint16_t*)(ws + 68 * MB);   // 32MB
  uint16_t* Hlo  = (uint16_t*)(ws + 100 * MB);  // 32MB
  uint16_t* Shi  = (uint16_t*)(ws + 132 * MB);  // 32MB (dead after gemm1)
  uint16_t* Slo  = (uint16_t*)(ws + 164 * MB);  // 32MB (dead after gemm1)
  float*    SC   = (float*)(ws + 132 * MB);     // 64MB scores, aliases Shi/Slo
  uint16_t* PR   = (uint16_t*)(ws + 68 * MB);   // 32MB probs, aliases Hhi

  const bool roomy = ws_size >= 229ull * MB;
  uint16_t* HT = roomy ? (uint16_t*)(ws + 196 * MB)   // 32MB dedicated
                       : (uint16_t*)(ws + 100 * MB);  // aliases Hlo (late write)

  // split inputs into f16 hi/lo
  split_f16_kernel<<<16384, 256, 0, stream>>>(S, Shi, Slo, 4 * 1024 * 1024);
  split_f16_kernel<<<1024, 256, 0, stream>>>(Ww, Whi, Wlo, 256 * 1024);
  if (roomy) {
    split_h_kernel<<<dim3(16, 16, 16), 256, 0, stream>>>(H, Hhi, Hlo, HT);
  } else {
    split_f16_kernel<<<16384, 256, 0, stream>>>(H, Hhi, Hlo, 4 * 1024 * 1024);
  }

  // S_ = S @ W^T + b   (GMAP 0: x = M-tile so lin%8 partitions A across XCDs)
  gemm_bt<true, 0, 0><<<dim3(128, 8, 1), 256, 0, stream>>>(
      Shi, Slo, Whi, Wlo, Pjhi, Pjlo, nullptr, nullptr, Wb,
      1024, 1024, 0, 0, 0);
  // scores = S_ @ H^T + mask  (GMAP 1: x = batch so lin%8 partitions batches)
  gemm_bt<true, 1, 1><<<dim3(16, 64, 1), 256, 0, stream>>>(
      Pjhi, Pjlo, Hhi, Hlo, nullptr, nullptr, SC, mask, nullptr,
      1024, 1024, 1048576, 1048576, 1048576);
  // P = softmax(scores) rowwise -> f16
  softmax_kernel<<<16384, 256, 0, stream>>>(SC, PR);
  if (!roomy) {
    transpose_f16_kernel<<<dim3(16, 16, 16), 256, 0, stream>>>(H, HT);
  }
  // out = P @ H  ==  P @ (H_T)^T
  gemm_bt<false, 2, 1><<<dim3(16, 64, 1), 256, 0, stream>>>(
      PR, nullptr, HT, nullptr, nullptr, nullptr, out, nullptr, nullptr,
      1024, 1024, 1048576, 1048576, 1048576);
}